// Round 5
// baseline (78.791 us; speedup 1.0000x reference)
//
#include <hip/hip_runtime.h>
#include <stdint.h>

#define SEQ   2048
#define BITS  256
#define HEADS 8
#define NPOS  4
#define MAXD  8
#define NBPN  12

typedef unsigned long long u64;
typedef unsigned int       u32;
typedef unsigned short     u16;

// ---- workspace layout (bytes) ----
#define OFF_TBL    0                         // 512 u64   (4096 B)
#define OFF_PACKED 4096                      // SEQ*4 u64 (65536 B)
#define OFF_AQ     (4096 + 65536)            // SEQ*HEADS u16 (32768 B)
#define OFF_AK     (4096 + 65536 + 32768)    // SEQ*HEADS u16 (32768 B)
#define OFF_AR     (4096 + 65536 + 65536)    // 9*HEADS u16 (144 B)

// Fused prep kernel (measured ~2-3 us incl. launch):
//   [0, 2048)    : pack tokens via ballot   (SEQ*BITS bits)
//   [2048, 2176) : pack table via ballot    (HEADS*4096 bits)
//   [2176, 2240) : Aq/Ak/Ar address parts
__global__ __launch_bounds__(256) void prep_kernel(
        const int* __restrict__ tokens, const int* __restrict__ head_idx,
        const float* __restrict__ table,
        u64* __restrict__ tblbits, u64* __restrict__ packed,
        u16* __restrict__ Aq, u16* __restrict__ Ak, u16* __restrict__ Ar) {
    const int bid = blockIdx.x, tid = threadIdx.x;
    if (bid < 2048) {
        int t = bid * 256 + tid;
        u64 m = __ballot(tokens[t] & 1);
        if ((tid & 63) == 0) packed[t >> 6] = m;
    } else if (bid < 2048 + 128) {
        int t = (bid - 2048) * 256 + tid;
        u64 m = __ballot(table[t] != 0.0f);
        if ((tid & 63) == 0) tblbits[t >> 6] = m;
    } else {
        int t = (bid - 2176) * 256 + tid;        // 0..16383
        int s = t >> 3, h = t & 7;
        const int* hi  = head_idx + h * NBPN;
        const int* tok = tokens + s * BITS;
        int aq = 0, ak = 0;
        #pragma unroll
        for (int k = 0; k < NBPN; ++k) {
            int idx = hi[k];
            if (idx < BITS)          aq += tok[idx] << k;
            else if (idx < 2 * BITS) ak += tok[idx - BITS] << k;
        }
        Aq[t] = (u16)aq;
        Ak[t] = (u16)ak;
        if (t < (MAXD + 1) * HEADS) {            // 72 threads also fill Ar
            int d = t / HEADS, hh = t % HEADS;
            const int* hi2 = head_idx + hh * NBPN;
            int ar = 0;
            #pragma unroll
            for (int k = 0; k < NBPN; ++k) {
                int idx = hi2[k];
                if (idx >= 2 * BITS) ar += ((d >> (idx - 2 * BITS)) & 1) << k;
            }
            Ar[t] = (u16)ar;
        }
    }
}

__device__ inline u64 shfl_xor_u64(u64 x, int o) {
    u32 lo = (u32)x, hi = (u32)(x >> 32);
    lo = __shfl_xor(lo, o, 64);
    hi = __shfl_xor(hi, o, 64);
    return ((u64)hi << 32) | lo;
}

// Wave-per-row: 1024 blocks x 128 threads; wave w owns row i = 2*blk + w.
// Table LDS load amortized over 2 rows; single __syncthreads; epilogue is a
// pure 6-step __shfl_xor butterfly (all lanes converge -> no broadcast, no
// cross-wave LDS combine); one float4 store per lane (4 bits each).
__global__ __launch_bounds__(128) void row_kernel(
        const u64* __restrict__ tblbits, const u64* __restrict__ packed,
        const u16* __restrict__ Aq, const u16* __restrict__ Ak,
        const u16* __restrict__ Ar, float* __restrict__ out) {

    __shared__ u32 tbl[HEADS * 128];          // 4 KB table bitmask (u32 words)
    __shared__ u16 aqar[2][MAXD + 1][HEADS];  // per-wave row bases

    const int tid  = threadIdx.x;
    const int lane = tid & 63, w = tid >> 6;
    const int i    = blockIdx.x * 2 + w;      // this wave's row

    const u32* tb32 = (const u32*)tblbits;
    #pragma unroll
    for (int q = 0; q < 8; ++q) tbl[tid + q * 128] = tb32[tid + q * 128];
    for (int e = lane; e < (MAXD + 1) * HEADS; e += 64) {
        int h = e & 7;
        aqar[w][e >> 3][h] = (u16)(Aq[i * HEADS + h] + Ar[e]);
    }
    __syncthreads();

    u32 a8[8];                                 // dist>=8 bases in registers
    #pragma unroll
    for (int h = 0; h < 8; ++h) a8[h] = aqar[w][MAXD][h];

    u64 acc0 = 0, acc1 = 0, acc2 = 0, acc3 = 0;
    int inc = 0;
    u64 bestkey = 0;

    // ---- peel: dist = lane in [0,8), j = i - dist ----
    if (lane < MAXD) {
        int j = i - lane;
        if (j >= 0) {
            const uint4 akv = *(const uint4*)(Ak + j * HEADS);
            int votes = 0;
            #pragma unroll
            for (int h = 0; h < 8; ++h) {
                u32 ak_h = ((&akv.x)[h >> 1] >> ((h & 1) * 16)) & 0xFFFFu;
                u32 addr = (u32)aqar[w][lane][h] + ak_h;
                votes += (int)((tbl[(h << 7) + (addr >> 5)] >> (addr & 31)) & 1u);
            }
            int att = (votes >= HEADS / 2) ? 1 : 0;
            u64 m = (u64)0 - (u64)att;
            const ulonglong2* pj = (const ulonglong2*)(packed + j * 4);
            ulonglong2 pA = pj[0], pB = pj[1];
            acc0 ^= pA.x & m; acc1 ^= pA.y & m;
            acc2 ^= pB.x & m; acc3 ^= pB.y & m;
            inc += att;
            u64 key = ((u64)(votes + 1) << 32) | (u64)(0x7FFFFFFF - j);
            if (key > bestkey) bestkey = key;
        }
    }

    // ---- main: j <= i - 8, branch-free base, prefetched ----
    const int ilim = i - MAXD;
    int j = lane;
    uint4 akv; ulonglong2 pA, pB;
    if (j <= ilim) {
        akv = *(const uint4*)(Ak + j * HEADS);
        const ulonglong2* pj = (const ulonglong2*)(packed + j * 4);
        pA = pj[0]; pB = pj[1];
    }
    while (j <= ilim) {
        const int jn = j + 64;
        uint4 akv_n; ulonglong2 pA_n, pB_n;
        if (jn <= ilim) {                      // prefetch next tile
            akv_n = *(const uint4*)(Ak + jn * HEADS);
            const ulonglong2* pjn = (const ulonglong2*)(packed + jn * 4);
            pA_n = pjn[0]; pB_n = pjn[1];
        }
        int votes = 0;
        #pragma unroll
        for (int h = 0; h < 8; ++h) {
            u32 ak_h = ((&akv.x)[h >> 1] >> ((h & 1) * 16)) & 0xFFFFu;
            u32 addr = a8[h] + ak_h;           // < 4096 (disjoint bit masks)
            votes += (int)((tbl[(h << 7) + (addr >> 5)] >> (addr & 31)) & 1u);
        }
        int att = (votes >= HEADS / 2) ? 1 : 0;
        u64 m = (u64)0 - (u64)att;
        acc0 ^= pA.x & m; acc1 ^= pA.y & m;
        acc2 ^= pB.x & m; acc3 ^= pB.y & m;
        inc += att;
        u64 key = ((u64)(votes + 1) << 32) | (u64)(0x7FFFFFFF - j);
        if (key > bestkey) bestkey = key;
        j = jn; akv = akv_n; pA = pA_n; pB = pB_n;
    }

    // ---- wave-local butterfly reduce: all 64 lanes converge ----
    #pragma unroll
    for (int o = 1; o < 64; o <<= 1) {
        acc0 ^= shfl_xor_u64(acc0, o);
        acc1 ^= shfl_xor_u64(acc1, o);
        acc2 ^= shfl_xor_u64(acc2, o);
        acc3 ^= shfl_xor_u64(acc3, o);
        inc  += __shfl_xor(inc, o, 64);
        u64 k2 = shfl_xor_u64(bestkey, o);
        if (k2 > bestkey) bestkey = k2;
    }

    // ---- store: 4 bits per lane -> one float4 (1 KB/wave coalesced) ----
    int wsel = lane >> 4;                      // which u64 word
    u64 word;
    if (inc > 0) {
        word = (wsel < 2) ? (wsel == 0 ? acc0 : acc1)
                          : (wsel == 2 ? acc2 : acc3);
    } else {
        int bestj = 0x7FFFFFFF - (int)(bestkey & 0xFFFFFFFFu);
        word = packed[bestj * 4 + wsel];
    }
    int sh = (lane & 15) * 4;
    float4 o4 = make_float4((float)((word >> sh) & 1ull),
                            (float)((word >> (sh + 1)) & 1ull),
                            (float)((word >> (sh + 2)) & 1ull),
                            (float)((word >> (sh + 3)) & 1ull));
    *(float4*)(out + i * BITS + lane * 4) = o4;
}

extern "C" void kernel_launch(void* const* d_in, const int* in_sizes, int n_in,
                              void* d_out, int out_size, void* d_ws, size_t ws_size,
                              hipStream_t stream) {
    const int*   tokens   = (const int*)d_in[0];
    const int*   head_idx = (const int*)d_in[1];
    const float* table    = (const float*)d_in[2];
    float*       out      = (float*)d_out;
    char*        ws       = (char*)d_ws;

    u64* tblbits = (u64*)(ws + OFF_TBL);
    u64* packed  = (u64*)(ws + OFF_PACKED);
    u16* Aq      = (u16*)(ws + OFF_AQ);
    u16* Ak      = (u16*)(ws + OFF_AK);
    u16* Ar      = (u16*)(ws + OFF_AR);

    prep_kernel<<<2240, 256, 0, stream>>>(tokens, head_idx, table,
                                          tblbits, packed, Aq, Ak, Ar);
    row_kernel <<<SEQ / 2, 128, 0, stream>>>(tblbits, packed, Aq, Ak, Ar, out);
}

// Round 6
// 75.088 us; speedup vs baseline: 1.0493x; 1.0493x over previous
//
#include <hip/hip_runtime.h>
#include <stdint.h>

#define SEQ   2048
#define BITS  256
#define HEADS 8
#define NPOS  4
#define MAXD  8
#define NBPN  12

typedef unsigned long long u64;
typedef unsigned int       u32;
typedef unsigned short     u16;

// ---- workspace layout (bytes) ----
#define OFF_TBL    0                         // 512 u64   (4096 B)
#define OFF_PACKED 4096                      // SEQ*4 u64 (65536 B)
#define OFF_AQ     (4096 + 65536)            // SEQ*HEADS u16 (32768 B)
#define OFF_AK     (4096 + 65536 + 32768)    // SEQ*HEADS u16 (32768 B)
#define OFF_AR     (4096 + 65536 + 65536)    // 9*HEADS u16 (144 B)

// Fused prep kernel (~2-3 us incl. launch):
//   [0, 2048)    : pack tokens via ballot   (SEQ*BITS bits)
//   [2048, 2176) : pack table via ballot    (HEADS*4096 bits)
//   [2176, 2240) : Aq/Ak/Ar address parts
__global__ __launch_bounds__(256) void prep_kernel(
        const int* __restrict__ tokens, const int* __restrict__ head_idx,
        const float* __restrict__ table,
        u64* __restrict__ tblbits, u64* __restrict__ packed,
        u16* __restrict__ Aq, u16* __restrict__ Ak, u16* __restrict__ Ar) {
    const int bid = blockIdx.x, tid = threadIdx.x;
    if (bid < 2048) {
        int t = bid * 256 + tid;
        u64 m = __ballot(tokens[t] & 1);
        if ((tid & 63) == 0) packed[t >> 6] = m;
    } else if (bid < 2048 + 128) {
        int t = (bid - 2048) * 256 + tid;
        u64 m = __ballot(table[t] != 0.0f);
        if ((tid & 63) == 0) tblbits[t >> 6] = m;
    } else {
        int t = (bid - 2176) * 256 + tid;        // 0..16383
        int s = t >> 3, h = t & 7;
        const int* hi  = head_idx + h * NBPN;
        const int* tok = tokens + s * BITS;
        int aq = 0, ak = 0;
        #pragma unroll
        for (int k = 0; k < NBPN; ++k) {
            int idx = hi[k];
            if (idx < BITS)          aq += tok[idx] << k;
            else if (idx < 2 * BITS) ak += tok[idx - BITS] << k;
        }
        Aq[t] = (u16)aq;
        Ak[t] = (u16)ak;
        if (t < (MAXD + 1) * HEADS) {            // 72 threads also fill Ar
            int d = t / HEADS, hh = t % HEADS;
            const int* hi2 = head_idx + hh * NBPN;
            int ar = 0;
            #pragma unroll
            for (int k = 0; k < NBPN; ++k) {
                int idx = hi2[k];
                if (idx >= 2 * BITS) ar += ((d >> (idx - 2 * BITS)) & 1) << k;
            }
            Ar[t] = (u16)ar;
        }
    }
}

__device__ inline u64 shfl_down_u64(u64 x, int o) {
    u32 lo = (u32)x, hi = (u32)(x >> 32);
    lo = __shfl_down(lo, o, 64);
    hi = __shfl_down(hi, o, 64);
    return ((u64)hi << 32) | lo;
}

// One row per block, 2 waves (R4 structure — best measured at 75.7 us).
// Near-diagonal (dist<8) peeled to threads 0..7; main loop branch-free with
// register a8 base + next-iteration prefetch of Ak/packed. Wave-per-row (R5)
// regressed: it doubles the critical-path iterations of the deepest rows.
__global__ __launch_bounds__(128) void row_kernel(
        const u64* __restrict__ tblbits, const u64* __restrict__ packed,
        const u16* __restrict__ Aq, const u16* __restrict__ Ak,
        const u16* __restrict__ Ar, float* __restrict__ out) {

    __shared__ u32 tbl[HEADS * 128];       // 4 KB table bitmask (u32 words)
    __shared__ u16 aqar[MAXD + 1][HEADS];
    __shared__ u64 p_acc[2][4];
    __shared__ int p_inc[2];
    __shared__ u64 p_key[2];

    const int i   = blockIdx.x;
    const int tid = threadIdx.x;

    // stage table via 2x dwordx4 -> 2x ds_write_b128 per thread
    {
        const uint4* tb4 = (const uint4*)tblbits;
        uint4* tl4 = (uint4*)tbl;
        tl4[tid]       = tb4[tid];
        tl4[tid + 128] = tb4[tid + 128];
    }
    if (tid < (MAXD + 1) * HEADS) {
        int h = tid & 7;
        aqar[tid >> 3][h] = (u16)(Aq[i * HEADS + h] + Ar[tid]);
    }
    __syncthreads();

    u32 a8[8];                             // dist>=8 bases in registers
    #pragma unroll
    for (int h = 0; h < 8; ++h) a8[h] = aqar[MAXD][h];

    u64 acc0 = 0, acc1 = 0, acc2 = 0, acc3 = 0;
    int inc = 0;
    u64 bestkey = 0;

    // ---- peel: dist = tid in [0,8), j = i - dist ----
    if (tid < MAXD) {
        int j = i - tid;
        if (j >= 0) {
            const uint4 akv = *(const uint4*)(Ak + j * HEADS);
            int votes = 0;
            #pragma unroll
            for (int h = 0; h < 8; ++h) {
                u32 ak_h = ((&akv.x)[h >> 1] >> ((h & 1) * 16)) & 0xFFFFu;
                u32 addr = (u32)aqar[tid][h] + ak_h;
                votes += (int)((tbl[(h << 7) + (addr >> 5)] >> (addr & 31)) & 1u);
            }
            int att = (votes >= HEADS / 2) ? 1 : 0;
            u64 m = (u64)0 - (u64)att;
            const ulonglong2* pj = (const ulonglong2*)(packed + j * 4);
            ulonglong2 pA = pj[0], pB = pj[1];
            acc0 ^= pA.x & m; acc1 ^= pA.y & m;
            acc2 ^= pB.x & m; acc3 ^= pB.y & m;
            inc += att;
            u64 key = ((u64)(votes + 1) << 32) | (u64)(0x7FFFFFFF - j);
            if (key > bestkey) bestkey = key;
        }
    }

    // ---- main: j <= i - 8, branch-free base, prefetched ----
    const int ilim = i - MAXD;
    int j = tid;
    uint4 akv; ulonglong2 pA, pB;
    if (j <= ilim) {
        akv = *(const uint4*)(Ak + j * HEADS);
        const ulonglong2* pj = (const ulonglong2*)(packed + j * 4);
        pA = pj[0]; pB = pj[1];
    }
    while (j <= ilim) {
        const int jn = j + 128;
        uint4 akv_n; ulonglong2 pA_n, pB_n;
        if (jn <= ilim) {                  // prefetch next tile
            akv_n = *(const uint4*)(Ak + jn * HEADS);
            const ulonglong2* pjn = (const ulonglong2*)(packed + jn * 4);
            pA_n = pjn[0]; pB_n = pjn[1];
        }
        int votes = 0;
        #pragma unroll
        for (int h = 0; h < 8; ++h) {
            u32 ak_h = ((&akv.x)[h >> 1] >> ((h & 1) * 16)) & 0xFFFFu;
            u32 addr = a8[h] + ak_h;       // < 4096 (disjoint bit masks)
            votes += (int)((tbl[(h << 7) + (addr >> 5)] >> (addr & 31)) & 1u);
        }
        int att = (votes >= HEADS / 2) ? 1 : 0;
        u64 m = (u64)0 - (u64)att;
        acc0 ^= pA.x & m; acc1 ^= pA.y & m;
        acc2 ^= pB.x & m; acc3 ^= pB.y & m;
        inc += att;
        u64 key = ((u64)(votes + 1) << 32) | (u64)(0x7FFFFFFF - j);
        if (key > bestkey) bestkey = key;
        j = jn; akv = akv_n; pA = pA_n; pB = pB_n;
    }

    #pragma unroll
    for (int o = 32; o > 0; o >>= 1) {
        acc0 ^= shfl_down_u64(acc0, o);
        acc1 ^= shfl_down_u64(acc1, o);
        acc2 ^= shfl_down_u64(acc2, o);
        acc3 ^= shfl_down_u64(acc3, o);
        inc  += __shfl_down(inc, o, 64);
        u64 k2 = shfl_down_u64(bestkey, o);
        if (k2 > bestkey) bestkey = k2;
    }
    int wave = tid >> 6;
    if ((tid & 63) == 0) {
        p_acc[wave][0] = acc0; p_acc[wave][1] = acc1;
        p_acc[wave][2] = acc2; p_acc[wave][3] = acc3;
        p_inc[wave] = inc; p_key[wave] = bestkey;
    }
    __syncthreads();

    u64 f0 = p_acc[0][0] ^ p_acc[1][0];
    u64 f1 = p_acc[0][1] ^ p_acc[1][1];
    u64 f2 = p_acc[0][2] ^ p_acc[1][2];
    u64 f3 = p_acc[0][3] ^ p_acc[1][3];
    int finc = p_inc[0] + p_inc[1];
    u64 fk = (p_key[0] > p_key[1]) ? p_key[0] : p_key[1];

    int b0   = tid * 2;                    // 2 output bits per thread
    int wsel = tid >> 5;
    u64 word;
    if (finc > 0) {
        word = (wsel < 2) ? (wsel == 0 ? f0 : f1) : (wsel == 2 ? f2 : f3);
    } else {
        int bestj = 0x7FFFFFFF - (int)(fk & 0xFFFFFFFFu);
        word = packed[bestj * 4 + wsel];
    }
    int sh = b0 & 63;
    float2 o2 = make_float2((float)((word >> sh) & 1ull),
                            (float)((word >> (sh + 1)) & 1ull));
    *(float2*)(out + i * BITS + b0) = o2;
}

extern "C" void kernel_launch(void* const* d_in, const int* in_sizes, int n_in,
                              void* d_out, int out_size, void* d_ws, size_t ws_size,
                              hipStream_t stream) {
    const int*   tokens   = (const int*)d_in[0];
    const int*   head_idx = (const int*)d_in[1];
    const float* table    = (const float*)d_in[2];
    float*       out      = (float*)d_out;
    char*        ws       = (char*)d_ws;

    u64* tblbits = (u64*)(ws + OFF_TBL);
    u64* packed  = (u64*)(ws + OFF_PACKED);
    u16* Aq      = (u16*)(ws + OFF_AQ);
    u16* Ak      = (u16*)(ws + OFF_AK);
    u16* Ar      = (u16*)(ws + OFF_AR);

    prep_kernel<<<2240, 256, 0, stream>>>(tokens, head_idx, table,
                                          tblbits, packed, Aq, Ak, Ar);
    row_kernel <<<SEQ, 128, 0, stream>>>(tblbits, packed, Aq, Ak, Ar, out);
}